// Round 1
// baseline (674.910 us; speedup 1.0000x reference)
//
#include <hip/hip_runtime.h>
#include <stdint.h>

#define D 128
#define RNUM 4

typedef unsigned short u16;
typedef __attribute__((ext_vector_type(8))) short short8;
typedef __attribute__((ext_vector_type(4))) float floatx4;

__device__ inline u16 f2bf(float f) {
  union { float f; uint32_t u; } c; c.f = f;
  uint32_t r = (c.u + 0x7FFFu + ((c.u >> 16) & 1u)) >> 16;
  return (u16)r;
}

__device__ inline float fast_tanh(float v) {
  float a = fabsf(v);
  float e = __builtin_amdgcn_exp2f(a * 2.8853900817779268f);  // e^(2a)
  float t = 1.0f - 2.0f * __builtin_amdgcn_rcpf(e + 1.0f);
  return copysignf(t, v);
}

// Build Wt[r][col][k] (bf16, k<128 -> W_rel[r][k][col], else W_root) and bias[r][col]
__global__ void prep_kernel(const float* __restrict__ W_rel, const float* __restrict__ b_rel,
                            const float* __restrict__ W_root, const float* __restrict__ b_root,
                            u16* __restrict__ Wt, float* __restrict__ bias) {
  int idx = blockIdx.x * 256 + threadIdx.x;   // over RNUM*128*256
  if (idx < RNUM * D) bias[idx] = b_rel[idx] + b_root[idx];
  if (idx >= RNUM * D * 2 * D) return;
  int k   = idx & 255;
  int col = (idx >> 8) & 127;
  int r   = idx >> 15;
  float v = (k < D) ? W_rel[((size_t)r * D + k) * D + col]
                    : W_root[((size_t)r * D + (k - D)) * D + col];
  Wt[idx] = f2bf(v);
}

// One wave per edge; lane covers 2 components.
__global__ void scatter_kernel(const float* __restrict__ x, const int* __restrict__ ei,
                               const int* __restrict__ ea, float* __restrict__ agg,
                               int E, int g0, int G) {
  int t = blockIdx.x * 256 + threadIdx.x;
  int e = t >> 6;
  int lane = t & 63;
  if (e >= E) return;
  int g = ea[e] - g0;
  if (g < 0 || g >= G) return;
  int src = ei[e];
  int dst = ei[E + e];
  const float2* xr = (const float2*)(x + (size_t)src * D);
  float2 v = xr[lane];
  float* p = agg + ((size_t)dst * G + g) * D + lane * 2;
  unsafeAtomicAdd(p, v.x);
  unsafeAtomicAdd(p + 1, v.y);
}

// 64 nodes per block, 256 threads = 4 waves; wave w owns cols [w*32, w*32+32).
// A (agg slots + x) staged in LDS as bf16 with 16B-chunk XOR swizzle; B from global (L2).
template <int G>
__global__ __launch_bounds__(256, 2) void fused_gemm_kernel(
    const float* __restrict__ agg, const float* __restrict__ x,
    const u16* __restrict__ Wt, const float* __restrict__ bias,
    float* __restrict__ out, int N, int g0, int accum) {
  __shared__ __align__(16) u16 sA[(G + 1) * 64 * D];

  const int tid = threadIdx.x;
  const int nodeBase = blockIdx.x * 64;

  // ---- stage A: [node][slot][chunk16B], slot<G = agg rel, slot==G = x ----
  constexpr int CH = 64 * (G + 1) * 16;
  for (int id = tid; id < CH; id += 256) {
    int c = id & 15;
    int rest = id >> 4;          // node*(G+1) + slot
    int slot = rest % (G + 1);
    int node = rest / (G + 1);
    int gnode = nodeBase + node;
    uint32_t p0, p1, p2, p3;
    if (gnode < N) {
      const float* s = (slot < G) ? (agg + (((size_t)gnode * G + slot) * D) + c * 8)
                                  : (x + ((size_t)gnode * D) + c * 8);
      float4 lo = *(const float4*)s;
      float4 hi = *(const float4*)(s + 4);
      p0 = (uint32_t)f2bf(lo.x) | ((uint32_t)f2bf(lo.y) << 16);
      p1 = (uint32_t)f2bf(lo.z) | ((uint32_t)f2bf(lo.w) << 16);
      p2 = (uint32_t)f2bf(hi.x) | ((uint32_t)f2bf(hi.y) << 16);
      p3 = (uint32_t)f2bf(hi.z) | ((uint32_t)f2bf(hi.w) << 16);
    } else {
      p0 = p1 = p2 = p3 = 0u;
    }
    int off = slot * (64 * D) + node * D + ((c ^ (node & 7)) * 8);
    uint4 pk; pk.x = p0; pk.y = p1; pk.z = p2; pk.w = p3;
    *(uint4*)&sA[off] = pk;
  }
  __syncthreads();

  // ---- compute ----
  const int l = tid & 63, w = tid >> 6;
  const int lrow = l & 15, lhi = l >> 4;

  floatx4 oacc[4][2];
#pragma unroll
  for (int m = 0; m < 4; ++m)
#pragma unroll
    for (int n = 0; n < 2; ++n) oacc[m][n] = (floatx4){0.f, 0.f, 0.f, 0.f};

  for (int r = 0; r < G; ++r) {
    floatx4 acc[4][2];
#pragma unroll
    for (int m = 0; m < 4; ++m)
#pragma unroll
      for (int n = 0; n < 2; ++n) acc[m][n] = (floatx4){0.f, 0.f, 0.f, 0.f};

#pragma unroll
    for (int ks = 0; ks < 8; ++ks) {
      const int slot = (ks < 4) ? r : G;
      const int cRead = (ks & 3) * 4 + lhi;
      short8 afr[4];
#pragma unroll
      for (int m = 0; m < 4; ++m) {
        int node = m * 16 + lrow;
        int off = slot * (64 * D) + node * D + ((cRead ^ (node & 7)) * 8);
        afr[m] = *(const short8*)&sA[off];
      }
      short8 bfr[2];
#pragma unroll
      for (int n = 0; n < 2; ++n) {
        int col = w * 32 + n * 16 + lrow;
        const u16* bp = Wt + (((size_t)(g0 + r) * D + col) * (2 * D) + ks * 32 + lhi * 8);
        bfr[n] = *(const short8*)bp;
      }
#pragma unroll
      for (int m = 0; m < 4; ++m)
#pragma unroll
        for (int n = 0; n < 2; ++n)
          acc[m][n] = __builtin_amdgcn_mfma_f32_16x16x32_bf16(afr[m], bfr[n], acc[m][n], 0, 0, 0);
    }

    float b0 = bias[(g0 + r) * D + w * 32 + lrow];
    float b1 = bias[(g0 + r) * D + w * 32 + 16 + lrow];
#pragma unroll
    for (int m = 0; m < 4; ++m)
#pragma unroll
      for (int n = 0; n < 2; ++n) {
        float bb = n ? b1 : b0;
#pragma unroll
        for (int j = 0; j < 4; ++j)
          oacc[m][n][j] += fast_tanh(acc[m][n][j] + bb);
      }
  }

  // ---- store: C row = lhi*4 + j, col = lane&15 ----
#pragma unroll
  for (int m = 0; m < 4; ++m) {
#pragma unroll
    for (int j = 0; j < 4; ++j) {
      int node = nodeBase + m * 16 + lhi * 4 + j;
      if (node < N) {
#pragma unroll
        for (int n = 0; n < 2; ++n) {
          int col = w * 32 + n * 16 + lrow;
          size_t oi = (size_t)node * D + col;
          float v = oacc[m][n][j];
          out[oi] = accum ? (out[oi] + v) : v;
        }
      }
    }
  }
}

extern "C" void kernel_launch(void* const* d_in, const int* in_sizes, int n_in,
                              void* d_out, int out_size, void* d_ws, size_t ws_size,
                              hipStream_t stream) {
  const float* x      = (const float*)d_in[0];
  const int*   ei     = (const int*)d_in[1];
  const int*   ea     = (const int*)d_in[2];
  const float* W_rel  = (const float*)d_in[3];
  const float* b_rel  = (const float*)d_in[4];
  const float* W_root = (const float*)d_in[5];
  const float* b_root = (const float*)d_in[6];
  float* out = (float*)d_out;

  const int N = in_sizes[0] / D;   // 100000
  const int E = in_sizes[2];       // 640000

  u16*   Wt   = (u16*)d_ws;                                   // 256 KB
  float* bias = (float*)((char*)d_ws + RNUM * D * 2 * D * 2); // +2 KB
  const size_t hdr = RNUM * D * 2 * D * 2 + RNUM * D * 4 + 1536; // pad to 264192
  float* agg = (float*)((char*)d_ws + 264192);
  size_t avail = (ws_size > 264192) ? ws_size - 264192 : 0;

  int G = 1;
  if (avail >= (size_t)N * 4 * D * sizeof(float)) G = 4;
  else if (avail >= (size_t)N * 2 * D * sizeof(float)) G = 2;
  (void)hdr;

  prep_kernel<<<(RNUM * D * 2 * D + 255) / 256, 256, 0, stream>>>(W_rel, b_rel, W_root, b_root, Wt, bias);

  const size_t aggBytes = (size_t)N * G * D * sizeof(float);
  const int scatterBlocks = (E * 64 + 255) / 256;
  const int gemmBlocks = (N + 63) / 64;

  for (int g0 = 0; g0 < RNUM; g0 += G) {
    (void)hipMemsetAsync(agg, 0, aggBytes, stream);
    scatter_kernel<<<scatterBlocks, 256, 0, stream>>>(x, ei, ea, agg, E, g0, G);
    int accum = (g0 > 0) ? 1 : 0;
    if (G == 4)
      fused_gemm_kernel<4><<<gemmBlocks, 256, 0, stream>>>(agg, x, Wt, bias, out, N, g0, accum);
    else if (G == 2)
      fused_gemm_kernel<2><<<gemmBlocks, 256, 0, stream>>>(agg, x, Wt, bias, out, N, g0, accum);
    else
      fused_gemm_kernel<1><<<gemmBlocks, 256, 0, stream>>>(agg, x, Wt, bias, out, N, g0, accum);
  }
}

// Round 2
// 594.076 us; speedup vs baseline: 1.1361x; 1.1361x over previous
//
#include <hip/hip_runtime.h>
#include <stdint.h>

#define D 128
#define RNUM 4
#define TM 32          // nodes per GEMM tile / bucket

typedef unsigned short u16;
typedef __attribute__((ext_vector_type(8))) short short8;
typedef __attribute__((ext_vector_type(4))) float floatx4;

__device__ inline u16 f2bf(float f) {
  union { float f; uint32_t u; } c; c.f = f;
  uint32_t r = (c.u + 0x7FFFu + ((c.u >> 16) & 1u)) >> 16;
  return (u16)r;
}
__device__ inline uint32_t pack2(float a, float b) {
  return (uint32_t)f2bf(a) | ((uint32_t)f2bf(b) << 16);
}

__device__ inline float fast_tanh(float v) {
  float a = fabsf(v);
  float e = __builtin_amdgcn_exp2f(a * 2.8853900817779268f);  // e^(2a)
  float t = 1.0f - 2.0f * __builtin_amdgcn_rcpf(e + 1.0f);
  return copysignf(t, v);
}

// Build Wt[r][col][k] (bf16; k<128 -> W_rel[r][k][col], else W_root[r][k-128][col]) and bias.
__global__ void prep_kernel(const float* __restrict__ W_rel, const float* __restrict__ b_rel,
                            const float* __restrict__ W_root, const float* __restrict__ b_root,
                            u16* __restrict__ Wt, float* __restrict__ bias) {
  int idx = blockIdx.x * 256 + threadIdx.x;
  if (idx < RNUM * D) bias[idx] = b_rel[idx] + b_root[idx];
  if (idx >= RNUM * D * 2 * D) return;
  int k   = idx & 255;
  int col = (idx >> 8) & 127;
  int r   = idx >> 15;
  float v = (k < D) ? W_rel[((size_t)r * D + k) * D + col]
                    : W_root[((size_t)r * D + (k - D)) * D + col];
  Wt[idx] = f2bf(v);
}

// counts[(dst>>5)*4 + rel]++
__global__ void hist_kernel(const int* __restrict__ ei, const int* __restrict__ ea,
                            uint32_t* __restrict__ counts, int E) {
  int t = blockIdx.x * 256 + threadIdx.x;
  if (t >= E) return;
  int dst = ei[E + t];
  int rel = ea[t];
  atomicAdd(&counts[(dst >> 5) * 4 + rel], 1u);
}

// Single-block exclusive scan over n (<=16384) counts -> offsets[0..n], cursor copy.
__global__ __launch_bounds__(1024) void scan_kernel(const uint32_t* __restrict__ counts,
                                                    uint32_t* __restrict__ offsets,
                                                    uint32_t* __restrict__ cursor, int n) {
  __shared__ uint32_t sums[1024];
  int t = threadIdx.x;
  uint32_t loc[16];
  uint32_t s = 0;
#pragma unroll
  for (int i = 0; i < 16; ++i) {
    int idx = t * 16 + i;
    uint32_t c = (idx < n) ? counts[idx] : 0u;
    loc[i] = s;
    s += c;
  }
  sums[t] = s;
  __syncthreads();
  for (int off = 1; off < 1024; off <<= 1) {
    uint32_t v = (t >= off) ? sums[t - off] : 0u;
    __syncthreads();
    sums[t] += v;
    __syncthreads();
  }
  uint32_t base = (t == 0) ? 0u : sums[t - 1];
#pragma unroll
  for (int i = 0; i < 16; ++i) {
    int idx = t * 16 + i;
    if (idx < n) {
      uint32_t v = base + loc[i];
      offsets[idx] = v;
      cursor[idx] = v;
    }
  }
  if (t == 1023) offsets[n] = sums[1023];
}

// recs[pos] = src | (local<<17), bucketed by ((dst>>5)*4 + rel)
__global__ void fill_kernel(const int* __restrict__ ei, const int* __restrict__ ea,
                            uint32_t* __restrict__ cursor, uint32_t* __restrict__ recs, int E) {
  int t = blockIdx.x * 256 + threadIdx.x;
  if (t >= E) return;
  int src = ei[t];
  int dst = ei[E + t];
  int rel = ea[t];
  uint32_t pos = atomicAdd(&cursor[(dst >> 5) * 4 + rel], 1u);
  recs[pos] = (uint32_t)src | ((uint32_t)(dst & 31) << 17);
}

// Fused gather-aggregate (fp32 LDS) -> bf16 convert (in place) -> MFMA GEMM + tanh + store.
// 256 threads = 4 waves; wave w aggregates relation w, then owns output cols [w*32, w*32+32).
__global__ __launch_bounds__(256, 2) void fused_kernel(
    const float* __restrict__ x, const uint32_t* __restrict__ recs,
    const uint32_t* __restrict__ offsets,
    const u16* __restrict__ Wt, const float* __restrict__ bias,
    float* __restrict__ out, int N) {
  __shared__ __align__(16) float aggF[4 * TM * D];   // 64 KB; bf16 slots overlay front 32 KB
  __shared__ __align__(16) u16 sX[TM * D];           // 8 KB  (x slot, swizzled bf16)

  const int tid = threadIdx.x;
  const int w = tid >> 6, l = tid & 63;
  const int nodeBase = blockIdx.x * TM;

  // ---- zero aggF ----
  float4 z = {0.f, 0.f, 0.f, 0.f};
#pragma unroll
  for (int i = 0; i < 16; ++i) ((float4*)aggF)[tid + i * 256] = z;

  // ---- stage x slot: swizzled bf16, 32 nodes x 16 chunks ----
#pragma unroll
  for (int k = 0; k < 2; ++k) {
    int id = tid + k * 256;
    int c = id & 15, node = id >> 4;
    int gnode = nodeBase + node;
    uint4 pk = {0u, 0u, 0u, 0u};
    if (gnode < N) {
      const float* s = x + (size_t)gnode * D + c * 8;
      float4 lo = *(const float4*)s;
      float4 hi = *(const float4*)(s + 4);
      pk.x = pack2(lo.x, lo.y); pk.y = pack2(lo.z, lo.w);
      pk.z = pack2(hi.x, hi.y); pk.w = pack2(hi.z, hi.w);
    }
    *(uint4*)&sX[node * D + ((c ^ (node & 7)) << 3)] = pk;
  }
  __syncthreads();

  // ---- phase A: wave w gathers + LDS-accumulates relation w ----
  {
    int seg = blockIdx.x * 4 + w;
    uint32_t i0 = offsets[seg], i1 = offsets[seg + 1];
    float* aw = aggF + w * (TM * D);
    uint32_t i = i0;
    for (; i + 4 <= i1; i += 4) {
      uint32_t r0 = recs[i], r1 = recs[i + 1], r2 = recs[i + 2], r3 = recs[i + 3];
      const float* p0 = x + (size_t)(r0 & 0x1FFFF) * D;
      const float* p1 = x + (size_t)(r1 & 0x1FFFF) * D;
      const float* p2 = x + (size_t)(r2 & 0x1FFFF) * D;
      const float* p3 = x + (size_t)(r3 & 0x1FFFF) * D;
      float a0 = p0[l], b0 = p0[l + 64];
      float a1 = p1[l], b1 = p1[l + 64];
      float a2 = p2[l], b2 = p2[l + 64];
      float a3 = p3[l], b3 = p3[l + 64];
      atomicAdd(&aw[(int)((r0 >> 17) & 31) * D + l], a0);
      atomicAdd(&aw[(int)((r0 >> 17) & 31) * D + 64 + l], b0);
      atomicAdd(&aw[(int)((r1 >> 17) & 31) * D + l], a1);
      atomicAdd(&aw[(int)((r1 >> 17) & 31) * D + 64 + l], b1);
      atomicAdd(&aw[(int)((r2 >> 17) & 31) * D + l], a2);
      atomicAdd(&aw[(int)((r2 >> 17) & 31) * D + 64 + l], b2);
      atomicAdd(&aw[(int)((r3 >> 17) & 31) * D + l], a3);
      atomicAdd(&aw[(int)((r3 >> 17) & 31) * D + 64 + l], b3);
    }
    for (; i < i1; ++i) {
      uint32_t r0 = recs[i];
      const float* p0 = x + (size_t)(r0 & 0x1FFFF) * D;
      float a0 = p0[l], b0 = p0[l + 64];
      atomicAdd(&aw[(int)((r0 >> 17) & 31) * D + l], a0);
      atomicAdd(&aw[(int)((r0 >> 17) & 31) * D + 64 + l], b0);
    }
  }
  __syncthreads();

  // ---- convert agg slots f32 -> swizzled bf16, in place (dst slot s = bytes [s*8K, s*8K+8K)) ----
#pragma unroll
  for (int s = 0; s < 4; ++s) {
    float4 v[4];
#pragma unroll
    for (int k = 0; k < 4; ++k) v[k] = ((const float4*)(aggF + s * (TM * D)))[tid + k * 256];
    __syncthreads();
#pragma unroll
    for (int k = 0; k < 4; ++k) {
      int f = tid + k * 256;                 // float4 unit within slot (0..1023)
      int node = f >> 5, c = (f >> 1) & 15, sub = f & 1;
      uint2 pk;
      pk.x = pack2(v[k].x, v[k].y);
      pk.y = pack2(v[k].z, v[k].w);
      *(uint2*)((u16*)aggF + s * (TM * D) + node * D + ((c ^ (node & 7)) << 3) + sub * 4) = pk;
    }
    __syncthreads();
  }

  // ---- MFMA phase ----
  const int lrow = l & 15, lhi = l >> 4;
  floatx4 oacc[2][2];
#pragma unroll
  for (int m = 0; m < 2; ++m)
#pragma unroll
    for (int n = 0; n < 2; ++n) oacc[m][n] = (floatx4){0.f, 0.f, 0.f, 0.f};

  for (int r = 0; r < RNUM; ++r) {
    floatx4 acc[2][2];
#pragma unroll
    for (int m = 0; m < 2; ++m)
#pragma unroll
      for (int n = 0; n < 2; ++n) acc[m][n] = (floatx4){0.f, 0.f, 0.f, 0.f};

#pragma unroll
    for (int ks = 0; ks < 8; ++ks) {
      const u16* Abase = (ks < 4) ? ((const u16*)aggF + r * (TM * D)) : sX;
      const int cRead = (ks & 3) * 4 + lhi;
      short8 afr[2];
#pragma unroll
      for (int m = 0; m < 2; ++m) {
        int node = m * 16 + lrow;
        afr[m] = *(const short8*)&Abase[node * D + ((cRead ^ (node & 7)) << 3)];
      }
      short8 bfr[2];
#pragma unroll
      for (int n = 0; n < 2; ++n) {
        int col = w * 32 + n * 16 + lrow;
        const u16* bp = Wt + ((size_t)(r * D + col) * (2 * D) + ks * 32 + lhi * 8);
        bfr[n] = *(const short8*)bp;
      }
#pragma unroll
      for (int m = 0; m < 2; ++m)
#pragma unroll
        for (int n = 0; n < 2; ++n)
          acc[m][n] = __builtin_amdgcn_mfma_f32_16x16x32_bf16(afr[m], bfr[n], acc[m][n], 0, 0, 0);
    }

    float b0 = bias[r * D + w * 32 + lrow];
    float b1 = bias[r * D + w * 32 + 16 + lrow];
#pragma unroll
    for (int m = 0; m < 2; ++m)
#pragma unroll
      for (int n = 0; n < 2; ++n) {
        float bb = n ? b1 : b0;
#pragma unroll
        for (int j = 0; j < 4; ++j)
          oacc[m][n][j] += fast_tanh(acc[m][n][j] + bb);
      }
  }

  // ---- store: C row = lhi*4 + j, col = lane&15 ----
#pragma unroll
  for (int m = 0; m < 2; ++m) {
#pragma unroll
    for (int j = 0; j < 4; ++j) {
      int node = nodeBase + m * 16 + lhi * 4 + j;
      if (node < N) {
#pragma unroll
        for (int n = 0; n < 2; ++n) {
          int col = w * 32 + n * 16 + lrow;
          out[(size_t)node * D + col] = oacc[m][n][j];
        }
      }
    }
  }
}

extern "C" void kernel_launch(void* const* d_in, const int* in_sizes, int n_in,
                              void* d_out, int out_size, void* d_ws, size_t ws_size,
                              hipStream_t stream) {
  const float* x      = (const float*)d_in[0];
  const int*   ei     = (const int*)d_in[1];
  const int*   ea     = (const int*)d_in[2];
  const float* W_rel  = (const float*)d_in[3];
  const float* b_rel  = (const float*)d_in[4];
  const float* W_root = (const float*)d_in[5];
  const float* b_root = (const float*)d_in[6];
  float* out = (float*)d_out;

  const int N = in_sizes[0] / D;   // 100000
  const int E = in_sizes[2];       // 640000
  const int NB = (N + TM - 1) / TM;       // 3125 buckets
  const int NSEG = NB * RNUM;             // 12500 segments

  // ws layout
  u16*      Wt      = (u16*)d_ws;                                  // 256 KB
  float*    bias    = (float*)((char*)d_ws + 262144);              // 2 KB
  uint32_t* counts  = (uint32_t*)((char*)d_ws + 264192);           // 50 KB
  uint32_t* offsets = (uint32_t*)((char*)d_ws + 314368);           // 50 KB
  uint32_t* cursor  = (uint32_t*)((char*)d_ws + 364544);           // 50 KB
  uint32_t* recs    = (uint32_t*)((char*)d_ws + 414720);           // 2.56 MB

  prep_kernel<<<(RNUM * D * 2 * D + 255) / 256, 256, 0, stream>>>(W_rel, b_rel, W_root, b_root, Wt, bias);
  (void)hipMemsetAsync(counts, 0, (size_t)NSEG * 4, stream);
  hist_kernel<<<(E + 255) / 256, 256, 0, stream>>>(ei, ea, counts, E);
  scan_kernel<<<1, 1024, 0, stream>>>(counts, offsets, cursor, NSEG);
  fill_kernel<<<(E + 255) / 256, 256, 0, stream>>>(ei, ea, cursor, recs, E);
  fused_kernel<<<NB, 256, 0, stream>>>(x, recs, offsets, Wt, bias, out, N);
}